// Round 1
// baseline (52.203 us; speedup 1.0000x reference)
//
#include <hip/hip_runtime.h>
#include <math.h>

// Problem constants (from reference)
constexpr int Bb = 8, Cc = 16, Hh = 96, Ww = 96;
constexpr int Ho = 94, Wo = 94;          // VALID 3x3
constexpr int NC = 4;                    // n_convs
constexpr int PLANE = Ho * Wo;           // 8836

__global__ __launch_bounds__(256)
void kan_conv_kernel(const float* __restrict__ x,
                     const float* __restrict__ base_w,        // (4,9)
                     const float* __restrict__ spline_w,      // (4,9,8)
                     const float* __restrict__ spline_scaler, // (4,9)
                     const float* __restrict__ grid,          // (12)
                     float* __restrict__ out)                 // (8,64,94,94)
{
    const int idx = blockIdx.x * blockDim.x + threadIdx.x;
    const int total = Bb * Cc * PLANE;
    if (idx >= total) return;

    const int wo = idx % Wo;
    int t = idx / Wo;
    const int ho = t % Ho;
    t /= Ho;
    const int c = t % Cc;
    const int b = t / Cc;

    // Grid knots (wave-uniform -> scalar loads)
    float g[12];
#pragma unroll
    for (int j = 0; j < 12; ++j) g[j] = grid[j];
    const float h  = g[1] - g[0];
    const float r1 = 1.0f / h;
    const float r2 = 1.0f / (2.0f * h);
    const float r3 = 1.0f / (3.0f * h);

    const float* xp = x + ((b * Cc + c) * Hh + ho) * Ww + wo;

    float acc0 = 0.f, acc1 = 0.f, acc2 = 0.f, acc3 = 0.f;

#pragma unroll
    for (int dy = 0; dy < 3; ++dy) {
#pragma unroll
        for (int dx = 0; dx < 3; ++dx) {
            const int i = dy * 3 + dx;
            const float v = xp[dy * Ww + dx];

            // silu
            const float sl = v / (1.0f + __expf(-v));

            // Cox-de Boor recursion, degree 0 -> 3
            float b0[11];
#pragma unroll
            for (int j = 0; j < 11; ++j)
                b0[j] = (v >= g[j] && v < g[j + 1]) ? 1.0f : 0.0f;
            float b1[10];
#pragma unroll
            for (int j = 0; j < 10; ++j)
                b1[j] = (v - g[j]) * r1 * b0[j] + (g[j + 2] - v) * r1 * b0[j + 1];
            float b2[9];
#pragma unroll
            for (int j = 0; j < 9; ++j)
                b2[j] = (v - g[j]) * r2 * b1[j] + (g[j + 3] - v) * r2 * b1[j + 1];
            float b3[8];
#pragma unroll
            for (int j = 0; j < 8; ++j)
                b3[j] = (v - g[j]) * r3 * b2[j] + (g[j + 4] - v) * r3 * b2[j + 1];

            // Weight application; scaler factored out of the g-loop.
#pragma unroll
            for (int cc = 0; cc < 4; ++cc) {
                const int wi = cc * 9 + i;
                float dot = 0.f;
#pragma unroll
                for (int gg = 0; gg < 8; ++gg)
                    dot = fmaf(b3[gg], spline_w[wi * 8 + gg], dot);
                float a = fmaf(sl, base_w[wi], spline_scaler[wi] * dot);
                if      (cc == 0) acc0 += a;
                else if (cc == 1) acc1 += a;
                else if (cc == 2) acc2 += a;
                else              acc3 += a;
            }
        }
    }

    float* op = out + ((size_t)(b * Cc + c) * NC) * PLANE + ho * Wo + wo;
    op[0 * PLANE] = acc0;
    op[1 * PLANE] = acc1;
    op[2 * PLANE] = acc2;
    op[3 * PLANE] = acc3;
}

extern "C" void kernel_launch(void* const* d_in, const int* in_sizes, int n_in,
                              void* d_out, int out_size, void* d_ws, size_t ws_size,
                              hipStream_t stream) {
    const float* x              = (const float*)d_in[0];
    const float* base_w         = (const float*)d_in[1];
    const float* spline_w       = (const float*)d_in[2];
    const float* spline_scaler  = (const float*)d_in[3];
    const float* grid           = (const float*)d_in[4];
    float* out = (float*)d_out;

    const int total = Bb * Cc * PLANE;           // 1,131,008
    const int block = 256;
    const int ngrid = (total + block - 1) / block; // 4418 exact
    kan_conv_kernel<<<ngrid, block, 0, stream>>>(x, base_w, spline_w,
                                                 spline_scaler, grid, out);
}

// Round 2
// 42.560 us; speedup vs baseline: 1.2266x; 1.2266x over previous
//
#include <hip/hip_runtime.h>
#include <math.h>

// Problem constants (from reference)
constexpr int Bb = 8, Cc = 16, Hh = 96, Ww = 96;
constexpr int Ho = 94, Wo = 94;          // VALID 3x3
constexpr int NC = 4;                    // n_convs
constexpr int PLANE = Ho * Wo;           // 8836

// Tiling
constexpr int TX = 32, TY = 16;          // output tile per block
constexpr int IX = TX + 2, IY = TY + 2;  // 34 x 18 input/feature tile
constexpr int NXT = 3;                   // ceil(94/32)
constexpr int NYT = 6;                   // ceil(94/16)
constexpr int FSTRIDE = 12;              // floats per pixel feature (padded to 48B for b128 align)

__global__ __launch_bounds__(256)
void kan_conv_kernel(const float* __restrict__ x,
                     const float* __restrict__ base_w,        // (4,9)
                     const float* __restrict__ spline_w,      // (4,9,8)
                     const float* __restrict__ spline_scaler, // (4,9)
                     const float* __restrict__ grid,          // (12)
                     float* __restrict__ out)                 // (8,64,94,94)
{
    __shared__ float feat[IY][IX][FSTRIDE];

    const int tid = threadIdx.x;
    int blk = blockIdx.x;
    const int xt = blk % NXT; blk /= NXT;
    const int yt = blk % NYT; blk /= NYT;
    const int c  = blk % Cc;
    const int b  = blk / Cc;
    const int ox0 = xt * TX, oy0 = yt * TY;

    const float g0   = grid[0];
    const float invh = 1.0f / (grid[1] - g0);

    const float* xplane = x + (size_t)(b * Cc + c) * Hh * Ww;

    // ---------- Phase 1: per-pixel features (silu + 8 cubic B-spline bases) ----------
    for (int p = tid; p < IX * IY; p += 256) {
        const int py = p / IX, px = p % IX;
        const int gy = oy0 + py, gx = ox0 + px;
        const float v = (gy < Hh && gx < Ww) ? xplane[gy * Ww + gx] : 0.0f;

        const float sl = v / (1.0f + __expf(-v));   // silu

        // Uniform-grid cubic B-spline: interval j, local coord t in [0,1)
        const float u = (v - g0) * invh;
        int j = (int)u;                              // floor for u>=0
        if (!(u >= 0.0f && u < 11.0f)) j = -100;     // outside grid -> all bases zero
        const float t  = u - (float)j;
        const float t2 = t * t, t3 = t2 * t;
        const float omt = 1.0f - t;
        const float B0 = (1.0f / 6.0f) * omt * omt * omt;          // basis index j-3
        const float B1 = (1.0f / 6.0f) * (3.0f * t3 - 6.0f * t2 + 4.0f);   // j-2
        const float B2 = (1.0f / 6.0f) * (-3.0f * t3 + 3.0f * t2 + 3.0f * t + 1.0f); // j-1
        const float B3 = (1.0f / 6.0f) * t3;                        // j

        float bb[8];
#pragma unroll
        for (int k = 0; k < 8; ++k) {
            float r = 0.0f;
            r = (j == k + 3) ? B0 : r;
            r = (j == k + 2) ? B1 : r;
            r = (j == k + 1) ? B2 : r;
            r = (j == k    ) ? B3 : r;
            bb[k] = r;
        }

        float4* fp = (float4*)&feat[py][px][0];
        fp[0] = make_float4(sl,    bb[0], bb[1], bb[2]);
        fp[1] = make_float4(bb[3], bb[4], bb[5], bb[6]);
        fp[2] = make_float4(bb[7], 0.0f,  0.0f,  0.0f);
    }

    __syncthreads();

    // ---------- Phase 2: 3x3 x 9-feature x 4-conv contraction, 2 outputs/thread ----------
    const int tx = tid & 31;        // 0..31
    const int ty = tid >> 5;        // 0..7, each thread covers output rows 2*ty, 2*ty+1
    const int ox = ox0 + tx;

    float acc[2][4] = {{0.f, 0.f, 0.f, 0.f}, {0.f, 0.f, 0.f, 0.f}};

#pragma unroll
    for (int dy4 = 0; dy4 < 4; ++dy4) {
#pragma unroll
        for (int dx = 0; dx < 3; ++dx) {
            const float4* fp = (const float4*)&feat[2 * ty + dy4][tx + dx][0];
            const float4 f0 = fp[0];
            const float4 f1 = fp[1];
            const float4 f2 = fp[2];
            const float fv[9] = {f0.x, f0.y, f0.z, f0.w, f1.x, f1.y, f1.z, f1.w, f2.x};

#pragma unroll
            for (int r = 0; r < 2; ++r) {
                const int dy = dy4 - r;
                if (dy < 0 || dy > 2) continue;
                const int i = dy * 3 + dx;
#pragma unroll
                for (int cv = 0; cv < 4; ++cv) {
                    const int wi = cv * 9 + i;
                    float dot = 0.0f;
#pragma unroll
                    for (int gg = 0; gg < 8; ++gg)
                        dot = fmaf(fv[1 + gg], spline_w[wi * 8 + gg], dot);
                    acc[r][cv] = fmaf(fv[0], base_w[wi],
                                 fmaf(spline_scaler[wi], dot, acc[r][cv]));
                }
            }
        }
    }

    // ---------- Stores: 4 conv planes, coalesced ----------
    float* obase = out + (size_t)((b * Cc + c) * NC) * PLANE;
#pragma unroll
    for (int r = 0; r < 2; ++r) {
        const int oy = oy0 + 2 * ty + r;
        if (ox < Wo && oy < Ho) {
            float* op = obase + oy * Wo + ox;
            op[0 * PLANE] = acc[r][0];
            op[1 * PLANE] = acc[r][1];
            op[2 * PLANE] = acc[r][2];
            op[3 * PLANE] = acc[r][3];
        }
    }
}

extern "C" void kernel_launch(void* const* d_in, const int* in_sizes, int n_in,
                              void* d_out, int out_size, void* d_ws, size_t ws_size,
                              hipStream_t stream) {
    const float* x             = (const float*)d_in[0];
    const float* base_w        = (const float*)d_in[1];
    const float* spline_w      = (const float*)d_in[2];
    const float* spline_scaler = (const float*)d_in[3];
    const float* grid          = (const float*)d_in[4];
    float* out = (float*)d_out;

    const int nblocks = Bb * Cc * NYT * NXT;  // 8*16*6*3 = 2304
    kan_conv_kernel<<<nblocks, 256, 0, stream>>>(x, base_w, spline_w,
                                                 spline_scaler, grid, out);
}